// Round 8
// baseline (33.660 us; speedup 1.0000x reference)
//
#include <hip/hip_runtime.h>

constexpr int N_NODES  = 4000000;
constexpr int N_GRAPHS = 4096;
constexpr int D_FEAT   = 8;
constexpr int N_CLS    = 10;
constexpr int WIN      = 16384;   // half-window for warm-start search (~16 sigma)

typedef float f32x4 __attribute__((ext_vector_type(4)));

// Fused kernel: one block per graph.
// 1) warm-started cooperative 32-ary lower_bound (3 ballot rounds typical,
//    verified bracket + full-range fallback for certainty)
// 2) unit-stride float4 stream, 4 independent accumulators (ILP-4)
// 3) parity-split wave reduction, mean + tiny linear epilogue
__global__ __launch_bounds__(256) void fused_pool_linear(
    const float* __restrict__ x,       // [N_NODES, 8]
    const int*   __restrict__ ids,     // [N_NODES] sorted
    const float* __restrict__ W,       // [N_CLS, D_FEAT]
    const float* __restrict__ bias,    // [N_CLS]
    float*       __restrict__ out)     // [N_GRAPHS, N_CLS]
{
    const f32x4* xf = (const f32x4*)x; // [N_NODES*2] flat float4 view
    int g    = blockIdx.x;
    int lane = threadIdx.x & 63;
    int half = lane >> 5;              // 0: search g, 1: search g+1
    int l32  = lane & 31;
    int target = g + half;

    // Warm start around the linear estimate; bracket-check, fallback if needed.
    int est = (int)((long long)target * N_NODES / N_GRAPHS);
    int lo = est - WIN; if (lo < 0) lo = 0;
    int hi = est + WIN; if (hi > N_NODES) hi = N_NODES;
    {
        bool okL = (lo == 0)       || (ids[lo - 1] < target);
        bool okR = (hi == N_NODES) || (ids[hi] >= target);
        if (!(okL && okR)) { lo = 0; hi = N_NODES; }  // rare; correctness net
    }

    // 32-ary cooperative lower_bound: first idx with ids[idx] >= target.
    // (lo,hi uniform within each 32-lane half; halves may diverge safely —
    //  each half reads only its own 32 bits of the ballot.)
    while (hi - lo > 32) {
        int chunk = (hi - lo + 31) >> 5;
        int pos = lo + l32 * chunk;
        int v = (pos < hi) ? ids[pos] : 0x7fffffff;
        unsigned long long m = __ballot(v < target);
        unsigned int mm = half ? (unsigned int)(m >> 32) : (unsigned int)m;
        int cnt = __popc(mm);
        int nlo = cnt ? lo + (cnt - 1) * chunk + 1 : lo;
        int nhi = (cnt < 32) ? min(lo + cnt * chunk, hi) : hi;
        lo = nlo; hi = nhi;
    }
    {   // final round, chunk = 1
        int pos = lo + l32;
        int v = (pos < hi) ? ids[pos] : 0x7fffffff;
        unsigned long long m = __ballot(v < target);
        unsigned int mm = half ? (unsigned int)(m >> 32) : (unsigned int)m;
        lo += __popc(mm);
    }
    int s = __shfl(lo, 0);             // lower_bound(g)
    int e = __shfl(lo, 32);            // lower_bound(g+1)
    int len  = e - s;
    int endf = 2 * e;                  // end in float4 units

    // Unit-stride one-pass stream, 4 loads in flight via 4 accumulators.
    // Slot offsets are even multiples of 256 -> thread parity fixes its
    // feature half (even threads: feats 0-3, odd: feats 4-7).
    f32x4 a0 = (f32x4)(0.f), a1 = (f32x4)(0.f),
          a2 = (f32x4)(0.f), a3 = (f32x4)(0.f);
    for (int i = 2 * s + (int)threadIdx.x; i < endf; i += 1024) {
        a0 += xf[i];
        if (i + 256 < endf) a1 += xf[i + 256];
        if (i + 512 < endf) a2 += xf[i + 512];
        if (i + 768 < endf) a3 += xf[i + 768];
    }
    f32x4 acc = (a0 + a1) + (a2 + a3);

    // Butterfly over even offsets (sums each parity class separately).
    #pragma unroll
    for (int off = 32; off >= 2; off >>= 1) {
        acc.x += __shfl_xor(acc.x, off);
        acc.y += __shfl_xor(acc.y, off);
        acc.z += __shfl_xor(acc.z, off);
        acc.w += __shfl_xor(acc.w, off);
    }
    // Exchange halves across parity.
    f32x4 other;
    other.x = __shfl_xor(acc.x, 1);
    other.y = __shfl_xor(acc.y, 1);
    other.z = __shfl_xor(acc.z, 1);
    other.w = __shfl_xor(acc.w, 1);

    __shared__ float red[4][D_FEAT];
    __shared__ float mean[D_FEAT];
    int wid = threadIdx.x >> 6;
    if (lane == 0) {   // lane 0 is even: acc = feats 0-3, other = feats 4-7
        red[wid][0] = acc.x;   red[wid][1] = acc.y;
        red[wid][2] = acc.z;   red[wid][3] = acc.w;
        red[wid][4] = other.x; red[wid][5] = other.y;
        red[wid][6] = other.z; red[wid][7] = other.w;
    }
    __syncthreads();
    if (threadIdx.x < D_FEAT) {
        float v = red[0][threadIdx.x] + red[1][threadIdx.x]
                + red[2][threadIdx.x] + red[3][threadIdx.x];
        mean[threadIdx.x] = v / (float)len;
    }
    __syncthreads();
    if (threadIdx.x < N_CLS) {
        const float* w = W + (size_t)threadIdx.x * D_FEAT;
        float a = bias[threadIdx.x];
        #pragma unroll
        for (int j = 0; j < D_FEAT; ++j)
            a += mean[j] * w[j];
        out[(size_t)g * N_CLS + threadIdx.x] = a;
    }
}

extern "C" void kernel_launch(void* const* d_in, const int* in_sizes, int n_in,
                              void* d_out, int out_size, void* d_ws, size_t ws_size,
                              hipStream_t stream) {
    const float* x   = (const float*)d_in[0];   // [4M, 8] f32
    const int*   ids = (const int*)d_in[1];     // [4M] sorted segment ids
    // d_in[2] input_ids, d_in[3] attention_mask: unused by the forward
    const float* W   = (const float*)d_in[4];   // [10, 8]
    const float* b   = (const float*)d_in[5];   // [10]
    float*       out = (float*)d_out;           // [4096, 10]

    fused_pool_linear<<<N_GRAPHS, 256, 0, stream>>>(x, ids, W, b, out);
}

// Round 9
// 29.889 us; speedup vs baseline: 1.1262x; 1.1262x over previous
//
#include <hip/hip_runtime.h>

constexpr int N_NODES  = 4000000;
constexpr int N_GRAPHS = 4096;
constexpr int D_FEAT   = 8;
constexpr int N_CLS    = 10;
constexpr int GPB      = 4;       // graphs per block: one per wave
constexpr int WIN      = 16384;   // half-window for warm-start search (~16 sigma)

typedef float f32x4 __attribute__((ext_vector_type(4)));

// One graph per WAVE. Each wave: warm-started 32-ary lower_bound for its
// [s,e), unit-stride float4 stream (~30 float4/lane, ILP-4), wave-local
// parity-split reduction. No __syncthreads in the hot path; one barrier
// before the 40-thread linear epilogue.
__global__ __launch_bounds__(256) void fused_pool_linear(
    const float* __restrict__ x,       // [N_NODES, 8]
    const int*   __restrict__ ids,     // [N_NODES] sorted
    const float* __restrict__ W,       // [N_CLS, D_FEAT]
    const float* __restrict__ bias,    // [N_CLS]
    float*       __restrict__ out)     // [N_GRAPHS, N_CLS]
{
    const f32x4* xf = (const f32x4*)x; // [N_NODES*2] flat float4 view
    int wid  = threadIdx.x >> 6;       // wave index in block
    int lane = threadIdx.x & 63;
    int g    = blockIdx.x * GPB + wid; // this wave's graph

    int half = lane >> 5;              // 0: search g, 1: search g+1
    int l32  = lane & 31;
    int target = g + half;

    // Warm start around the linear estimate; bracket-check, fallback if bad.
    int est = (int)((long long)target * N_NODES / N_GRAPHS);
    int lo = est - WIN; if (lo < 0) lo = 0;
    int hi = est + WIN; if (hi > N_NODES) hi = N_NODES;
    {
        bool okL = (lo == 0)       || (ids[lo - 1] < target);
        bool okR = (hi == N_NODES) || (ids[hi] >= target);
        if (!(okL && okR)) { lo = 0; hi = N_NODES; }  // ~never; correctness net
    }

    // 32-ary cooperative lower_bound (each 32-lane half searches its target).
    while (hi - lo > 32) {
        int chunk = (hi - lo + 31) >> 5;
        int pos = lo + l32 * chunk;
        int v = (pos < hi) ? ids[pos] : 0x7fffffff;
        unsigned long long m = __ballot(v < target);
        unsigned int mm = half ? (unsigned int)(m >> 32) : (unsigned int)m;
        int cnt = __popc(mm);
        int nlo = cnt ? lo + (cnt - 1) * chunk + 1 : lo;
        int nhi = (cnt < 32) ? min(lo + cnt * chunk, hi) : hi;
        lo = nlo; hi = nhi;
    }
    {   // final round, chunk = 1
        int pos = lo + l32;
        int v = (pos < hi) ? ids[pos] : 0x7fffffff;
        unsigned long long m = __ballot(v < target);
        unsigned int mm = half ? (unsigned int)(m >> 32) : (unsigned int)m;
        lo += __popc(mm);
    }
    int s = __shfl(lo, 0);             // lower_bound(g)
    int e = __shfl(lo, 32);            // lower_bound(g+1)
    int len  = e - s;
    int endf = 2 * e;                  // end in float4 units

    // Per-wave unit-stride stream: lane i reads float4 (2s+i), stride 64.
    // Lane parity fixes its feature half (even: feats 0-3, odd: 4-7).
    // ILP-4: offsets 0,64,128,192; ~7 steady iterations.
    f32x4 a0 = (f32x4)(0.f), a1 = (f32x4)(0.f),
          a2 = (f32x4)(0.f), a3 = (f32x4)(0.f);
    for (int i = 2 * s + lane; i < endf; i += 256) {
        a0 += xf[i];
        if (i +  64 < endf) a1 += xf[i +  64];
        if (i + 128 < endf) a2 += xf[i + 128];
        if (i + 192 < endf) a3 += xf[i + 192];
    }
    f32x4 acc = (a0 + a1) + (a2 + a3);

    // Butterfly over even offsets (sums each parity class separately).
    #pragma unroll
    for (int off = 32; off >= 2; off >>= 1) {
        acc.x += __shfl_xor(acc.x, off);
        acc.y += __shfl_xor(acc.y, off);
        acc.z += __shfl_xor(acc.z, off);
        acc.w += __shfl_xor(acc.w, off);
    }
    // Exchange halves across parity.
    f32x4 other;
    other.x = __shfl_xor(acc.x, 1);
    other.y = __shfl_xor(acc.y, 1);
    other.z = __shfl_xor(acc.z, 1);
    other.w = __shfl_xor(acc.w, 1);

    __shared__ float red[GPB][D_FEAT];
    __shared__ float linv[GPB];
    if (lane == 0) {   // lane 0 is even: acc = feats 0-3, other = feats 4-7
        red[wid][0] = acc.x;   red[wid][1] = acc.y;
        red[wid][2] = acc.z;   red[wid][3] = acc.w;
        red[wid][4] = other.x; red[wid][5] = other.y;
        red[wid][6] = other.z; red[wid][7] = other.w;
        linv[wid]   = 1.0f / (float)len;
    }
    __syncthreads();
    if (threadIdx.x < GPB * N_CLS) {       // 40 threads
        int j = threadIdx.x / N_CLS;       // wave slot
        int c = threadIdx.x % N_CLS;       // class
        float inv = linv[j];
        const float* w = W + (size_t)c * D_FEAT;
        float a = bias[c];
        #pragma unroll
        for (int k = 0; k < D_FEAT; ++k)
            a += (red[j][k] * inv) * w[k];
        out[((size_t)blockIdx.x * GPB + j) * N_CLS + c] = a;
    }
}

extern "C" void kernel_launch(void* const* d_in, const int* in_sizes, int n_in,
                              void* d_out, int out_size, void* d_ws, size_t ws_size,
                              hipStream_t stream) {
    const float* x   = (const float*)d_in[0];   // [4M, 8] f32
    const int*   ids = (const int*)d_in[1];     // [4M] sorted segment ids
    // d_in[2] input_ids, d_in[3] attention_mask: unused by the forward
    const float* W   = (const float*)d_in[4];   // [10, 8]
    const float* b   = (const float*)d_in[5];   // [10]
    float*       out = (float*)d_out;           // [4096, 10]

    fused_pool_linear<<<N_GRAPHS / GPB, 256, 0, stream>>>(x, ids, W, b, out);
}